// Round 4
// baseline (221.723 us; speedup 1.0000x reference)
//
#include <hip/hip_runtime.h>

#define NSENT 64
#define NCAND 8192
#define LMAX  512
#define KOUT  128
#define TPB   512
#define CHUNK 2048
#define NCHUNK (NCAND / CHUNK)   // 4
#define NWIN   (NCAND / TPB)     // 16
#define SLOTS  (TPB / 64)        // 8

// ---------------------------------------------------------------------------
// Kernel A: 256 blocks (sentence s = bid>>2, chunk c = bid&3).
// Bitonic-sort 2048 u64 keys in LDS, write sorted chunk to ws.
// Key: high 32 = descending-orderable score bits, low 31 = (idx<<18)|(st<<9)|en
// ---------------------------------------------------------------------------
__global__ __launch_bounds__(TPB) void sort_chunks_kernel(
    const float* __restrict__ scores,
    const int*   __restrict__ starts,
    const int*   __restrict__ ends,
    unsigned long long* __restrict__ ws)
{
    __shared__ unsigned long long lk[CHUNK];
    const int  bid   = blockIdx.x;
    const int  sent  = bid >> 2;
    const int  chunk = bid & 3;
    const int  tid   = threadIdx.x;
    const long gbase = (long)sent * NCAND + (long)chunk * CHUNK;

    for (int i = tid; i < CHUNK; i += TPB) {
        unsigned u  = __float_as_uint(scores[gbase + i]);
        unsigned o  = (u & 0x80000000u) ? ~u : (u | 0x80000000u); // asc-orderable
        unsigned d  = ~o;                                          // descending
        unsigned st = (unsigned)starts[gbase + i];
        unsigned en = (unsigned)ends[gbase + i];
        unsigned gi = (unsigned)(chunk * CHUNK + i);               // idx in sentence
        lk[i] = ((unsigned long long)d << 32) | (gi << 18) | (st << 9) | en;
    }

    for (int k = 2; k <= CHUNK; k <<= 1) {
        for (int j = k >> 1; j > 0; j >>= 1) {
            __syncthreads();
            for (int p = tid; p < CHUNK / 2; p += TPB) {
                int low = p & (j - 1);
                int i   = ((p - low) << 1) | low;
                int q   = i | j;
                unsigned long long a = lk[i];
                unsigned long long b = lk[q];
                bool up = ((i & k) == 0);
                if ((a > b) == up) { lk[i] = b; lk[q] = a; }
            }
        }
    }
    __syncthreads();

    unsigned long long* wo = ws + (long)bid * CHUNK;
    for (int i = tid; i < CHUNK; i += TPB) wo[i] = lk[i];
}

// ---------------------------------------------------------------------------
// Kernel B: 64 blocks (one per sentence).
//  1. merge 4 sorted chunks (merge-path, 2 stages)
//  2. greedy non-crossing selection:
//     - window filter via dense {start->latest end, end->earliest start}
//       arrays (seb, int2) -- O(span width) independent LDS reads
//     - accept loop in wave 0 only: alive bits + payloads in registers,
//       ballots + shfl, no block barriers on the accept path
//     - seb rebuilt per window from delta accepts via LDS atomics
//  3. rank-sort of the <=128 selected by (start,end)
// ---------------------------------------------------------------------------
__global__ __launch_bounds__(TPB) void merge_greedy_kernel(
    const unsigned long long* __restrict__ ws,
    int* __restrict__ out)
{
    __shared__ unsigned long long keys[NCAND];   // 64 KiB
    __shared__ int2     seb[LMAX];               // {s2e, e2s} interleaved, 4 KiB
    __shared__ unsigned acc_list[KOUT];
    __shared__ unsigned long long amask[SLOTS];
    __shared__ int      n_sh;
    __shared__ unsigned mkbuf[KOUT];
    __shared__ unsigned paybuf[KOUT];

    const int sent = blockIdx.x;
    const int tid  = threadIdx.x;
    const unsigned long long* wi = ws + (long)sent * NCAND;

    // init greedy state (covered by the merge barriers below)
    if (tid < LMAX) seb[tid] = make_int2(-1, LMAX);
    if (tid == 0) n_sh = 0;

    for (int i = tid; i < NCAND; i += TPB) keys[i] = wi[i];
    __syncthreads();

    // ---- stage 1: merge (c0,c1)->[0,4096), (c2,c3)->[4096,8192) ------------
    {
        const int pair = tid >> 8;
        const int o    = (tid & 255) * 16;
        const unsigned long long* A = keys + pair * 4096;
        const unsigned long long* B = A + CHUNK;
        int lo = (o > CHUNK) ? o - CHUNK : 0;
        int hi = (o < CHUNK) ? o : CHUNK;
        while (lo < hi) {
            int mid = (lo + hi) >> 1;
            if (A[mid] <= B[o - 1 - mid]) lo = mid + 1; else hi = mid;
        }
        int i = lo, j = o - lo;
        unsigned long long r[16];
        #pragma unroll
        for (int x = 0; x < 16; ++x) {
            bool ta = (j >= CHUNK) || (i < CHUNK && A[i] <= B[j]);
            r[x] = ta ? A[i++] : B[j++];
        }
        __syncthreads();
        unsigned long long* O = keys + pair * 4096 + o;
        #pragma unroll
        for (int x = 0; x < 16; ++x) O[x] = r[x];
    }
    __syncthreads();

    // ---- stage 2: merge [0,4096)+[4096,8192) -> [0,8192) -------------------
    {
        const int o = tid * 16;
        const unsigned long long* A = keys;
        const unsigned long long* B = keys + 4096;
        int lo = (o > 4096) ? o - 4096 : 0;
        int hi = (o < 4096) ? o : 4096;
        while (lo < hi) {
            int mid = (lo + hi) >> 1;
            if (A[mid] <= B[o - 1 - mid]) lo = mid + 1; else hi = mid;
        }
        int i = lo, j = o - lo;
        unsigned long long r[16];
        #pragma unroll
        for (int x = 0; x < 16; ++x) {
            bool ta = (j >= 4096) || (i < 4096 && A[i] <= B[j]);
            r[x] = ta ? A[i++] : B[j++];
        }
        __syncthreads();
        #pragma unroll
        for (int x = 0; x < 16; ++x) keys[o + x] = r[x];
    }

    // ---- greedy non-crossing selection -------------------------------------
    for (int w = 0; w < NWIN; ++w) {
        const int cb = w * TPB;
        __syncthreads();                       // (1) seb / n_sh from prev window
        const int n0 = n_sh;
        if (n0 >= KOUT) break;                 // uniform

        // window filter: crossing iff exists j in (st,en] with s2e[j] > en,
        //                            or j in [st,en) with e2s[j] < st
        const unsigned pay = (unsigned)keys[cb + tid];
        const int en = (int)(pay & 511u);
        const int st = (int)((pay >> 9) & 511u);
        bool alive = true;
        for (int j = st; j <= en; ++j) {
            int2 v = seb[j];                   // one b64 read covers both arrays
            if ((j > st && v.x > en) || (j < en && v.y < st)) { alive = false; break; }
        }
        unsigned long long m = __ballot((int)alive);
        if ((tid & 63) == 0) amask[tid >> 6] = m;
        __syncthreads();                       // (2) amask visible to wave 0

        if (tid < 64) {                        // accept loop: wave 0, no barriers
            const int lane = tid;
            unsigned alive8 = 0;
            unsigned pv[SLOTS];
            #pragma unroll
            for (int s = 0; s < SLOTS; ++s) {  // slot s <-> thread s*64+lane
                unsigned long long mw = amask[s];
                alive8 |= (unsigned)((mw >> lane) & 1ull) << s;
                pv[s] = (unsigned)keys[cb + s * 64 + lane];
            }
            int n = n0;
            for (;;) {
                int swin = -1, lwin = 0;       // first alive, candidate order
                #pragma unroll
                for (int s = 0; s < SLOTS; ++s) {
                    unsigned long long b = __ballot((int)((alive8 >> s) & 1u));
                    if (swin < 0 && b) { swin = s; lwin = __ffsll((long long)b) - 1; }
                }
                if (swin < 0) break;           // window exhausted (uniform)

                unsigned myp = pv[0];          // static-index select of pv[swin]
                #pragma unroll
                for (int s = 1; s < SLOTS; ++s) myp = (swin == s) ? pv[s] : myp;
                const unsigned spay = (unsigned)__shfl((int)myp, lwin);
                const int sen = (int)(spay & 511u);
                const int sst = (int)((spay >> 9) & 511u);

                if (lane == 0) acc_list[n] = spay;
                ++n;
                if (lane == lwin) alive8 &= ~(1u << swin);
                if (n >= KOUT) break;

                if (alive8) {                  // retest survivors vs new span only
                    #pragma unroll
                    for (int s = 0; s < SLOTS; ++s) {
                        if ((alive8 >> s) & 1u) {
                            const int ce = (int)(pv[s] & 511u);
                            const int cs = (int)((pv[s] >> 9) & 511u);
                            const bool c = (cs < sst && sst <= ce && sen > ce) ||
                                           (sst < cs && sen >= cs && sen < ce);
                            if (c) alive8 &= ~(1u << s);
                        }
                    }
                }
            }
            if (lane == 0) n_sh = n;
        }
        __syncthreads();                       // (3) acc_list / n_sh visible

        // rebuild seb from this window's delta accepts (parallel atomics)
        const int n1 = n_sh;
        if (tid < n1 - n0) {
            unsigned ap = acc_list[n0 + tid];
            int ae = (int)(ap & 511u), as = (int)((ap >> 9) & 511u);
            atomicMax(&seb[as].x, ae);
            atomicMin(&seb[ae].y, as);
        }
    }
    __syncthreads();

    // ---- final (start,end) rank-sort + output ------------------------------
    const int n = n_sh;
    if (tid < KOUT) {
        unsigned pay = (tid < n) ? acc_list[tid] : acc_list[0];
        paybuf[tid] = pay;
        mkbuf[tid]  = ((pay & 0x3FFFFu) << 7) | (unsigned)tid;  // stable tie-break
    }
    __syncthreads();
    if (tid < KOUT) {
        unsigned mk = mkbuf[tid];
        int rank = 0;
        for (int t2 = 0; t2 < KOUT; ++t2)
            rank += (mkbuf[t2] < mk) ? 1 : 0;
        out[sent * KOUT + rank] = (int)(paybuf[tid] >> 18);
    }
}

// ---------------------------------------------------------------------------
// Fallback monolithic kernel (round-2, known-correct) if ws is too small.
// ---------------------------------------------------------------------------
__global__ __launch_bounds__(TPB) void extract_spans_mono(
    const float* __restrict__ scores,
    const int*   __restrict__ starts,
    const int*   __restrict__ ends,
    int*         __restrict__ out)
{
    __shared__ unsigned long long keys[NCAND];
    __shared__ unsigned acc_list[KOUT];
    __shared__ unsigned long long amask[TPB/64];
    __shared__ unsigned mkbuf[KOUT];
    __shared__ unsigned paybuf[KOUT];

    const int  sent = blockIdx.x;
    const int  tid  = threadIdx.x;
    const long base = (long)sent * NCAND;

    for (int i = tid; i < NCAND; i += TPB) {
        unsigned u = __float_as_uint(scores[base + i]);
        unsigned o = (u & 0x80000000u) ? ~u : (u | 0x80000000u);
        unsigned d = ~o;
        unsigned st = (unsigned)starts[base + i];
        unsigned en = (unsigned)ends[base + i];
        keys[i] = ((unsigned long long)d << 32) | ((unsigned)i << 18) | (st << 9) | en;
    }
    for (int k = 2; k <= NCAND; k <<= 1) {
        for (int j = k >> 1; j > 0; j >>= 1) {
            __syncthreads();
            for (int p = tid; p < NCAND / 2; p += TPB) {
                int low = p & (j - 1);
                int i   = ((p - low) << 1) | low;
                int q   = i | j;
                unsigned long long a = keys[i];
                unsigned long long b = keys[q];
                bool up = ((i & k) == 0);
                if ((a > b) == up) { keys[i] = b; keys[q] = a; }
            }
        }
    }
    __syncthreads();

    int  nn   = 0;
    bool done = false;
    for (int cb = 0; cb < NCAND && !done; cb += TPB) {
        const unsigned pay = (unsigned)keys[cb + tid];
        const int en = (int)(pay & 511u);
        const int st = (int)((pay >> 9) & 511u);
        bool alive = true;
        for (int a = 0; a < nn; ++a) {
            unsigned ap = acc_list[a];
            int ae = (int)(ap & 511u), as = (int)((ap >> 9) & 511u);
            if ((st < as && as <= en && ae > en) || (as < st && ae >= st && ae < en)) {
                alive = false; break;
            }
        }
        for (;;) {
            unsigned long long m = __ballot((int)alive);
            if ((tid & 63) == 0) amask[tid >> 6] = m;
            __syncthreads();
            int s = -1;
            #pragma unroll
            for (int w = 0; w < TPB / 64; ++w) {
                unsigned long long mw = amask[w];
                if (s < 0 && mw) s = (w << 6) + __ffsll((long long)mw) - 1;
            }
            __syncthreads();
            if (s < 0) break;
            unsigned spay = (unsigned)keys[cb + s];
            int sen = (int)(spay & 511u), sst = (int)((spay >> 9) & 511u);
            if (tid == 0) acc_list[nn] = spay;
            ++nn;
            if (nn == KOUT) { done = true; break; }
            if (alive) {
                alive = (tid != s) &&
                        !((st < sst && sst <= en && sen > en) ||
                          (sst < st && sen >= st && sen < en));
            }
        }
    }
    __syncthreads();
    if (tid < KOUT) {
        unsigned pay = (tid < nn) ? acc_list[tid] : acc_list[0];
        paybuf[tid] = pay;
        mkbuf[tid]  = ((pay & 0x3FFFFu) << 7) | (unsigned)tid;
    }
    __syncthreads();
    if (tid < KOUT) {
        unsigned mk = mkbuf[tid];
        int rank = 0;
        for (int t2 = 0; t2 < KOUT; ++t2)
            rank += (mkbuf[t2] < mk) ? 1 : 0;
        out[sent * KOUT + rank] = (int)(paybuf[tid] >> 18);
    }
}

extern "C" void kernel_launch(void* const* d_in, const int* in_sizes, int n_in,
                              void* d_out, int out_size, void* d_ws, size_t ws_size,
                              hipStream_t stream) {
    const float* scores = (const float*)d_in[0];
    const int*   starts = (const int*)d_in[1];
    const int*   ends   = (const int*)d_in[2];
    int*         out    = (int*)d_out;

    const size_t ws_needed = (size_t)NSENT * NCAND * sizeof(unsigned long long); // 4 MiB
    if (ws_size >= ws_needed) {
        unsigned long long* ws = (unsigned long long*)d_ws;
        sort_chunks_kernel<<<NSENT * NCHUNK, TPB, 0, stream>>>(scores, starts, ends, ws);
        merge_greedy_kernel<<<NSENT, TPB, 0, stream>>>(ws, out);
    } else {
        extract_spans_mono<<<NSENT, TPB, 0, stream>>>(scores, starts, ends, out);
    }
}

// Round 6
// 192.323 us; speedup vs baseline: 1.1529x; 1.1529x over previous
//
#include <hip/hip_runtime.h>

#define NSENT 64
#define NCAND 8192
#define LMAX  512
#define KOUT  128
#define TPB   512
#define CHUNK 2048
#define NCHUNK (NCAND / CHUNK)   // 4
#define NWIN   (NCAND / TPB)     // 16
#define SLOTS  (TPB / 64)        // 8

#if defined(__has_builtin)
#if __has_builtin(__builtin_amdgcn_readlane)
#define READLANE(v, l) __builtin_amdgcn_readlane((unsigned)(v), (unsigned)(l))
#endif
#endif
#ifndef READLANE
#define READLANE(v, l) ((unsigned)__shfl((int)(v), (int)(l)))
#endif

// ---------------------------------------------------------------------------
// Kernel A (unchanged from R3/R4): 256 blocks, bitonic-sort 2048 u64 -> ws.
// Key: high 32 = descending-orderable score bits, low 31 = (idx<<18)|(st<<9)|en
// ---------------------------------------------------------------------------
__global__ __launch_bounds__(TPB) void sort_chunks_kernel(
    const float* __restrict__ scores,
    const int*   __restrict__ starts,
    const int*   __restrict__ ends,
    unsigned long long* __restrict__ ws)
{
    __shared__ unsigned long long lk[CHUNK];
    const int  bid   = blockIdx.x;
    const int  sent  = bid >> 2;
    const int  chunk = bid & 3;
    const int  tid   = threadIdx.x;
    const long gbase = (long)sent * NCAND + (long)chunk * CHUNK;

    for (int i = tid; i < CHUNK; i += TPB) {
        unsigned u  = __float_as_uint(scores[gbase + i]);
        unsigned o  = (u & 0x80000000u) ? ~u : (u | 0x80000000u);
        unsigned d  = ~o;
        unsigned st = (unsigned)starts[gbase + i];
        unsigned en = (unsigned)ends[gbase + i];
        unsigned gi = (unsigned)(chunk * CHUNK + i);
        lk[i] = ((unsigned long long)d << 32) | (gi << 18) | (st << 9) | en;
    }

    for (int k = 2; k <= CHUNK; k <<= 1) {
        for (int j = k >> 1; j > 0; j >>= 1) {
            __syncthreads();
            for (int p = tid; p < CHUNK / 2; p += TPB) {
                int low = p & (j - 1);
                int i   = ((p - low) << 1) | low;
                int q   = i | j;
                unsigned long long a = lk[i];
                unsigned long long b = lk[q];
                bool up = ((i & k) == 0);
                if ((a > b) == up) { lk[i] = b; lk[q] = a; }
            }
        }
    }
    __syncthreads();

    unsigned long long* wo = ws + (long)bid * CHUNK;
    for (int i = tid; i < CHUNK; i += TPB) wo[i] = lk[i];
}

// ---------------------------------------------------------------------------
// Kernel B: merge (unchanged) + restructured greedy + parallel rank-sort.
// ---------------------------------------------------------------------------
__global__ __launch_bounds__(TPB) void merge_greedy_kernel(
    const unsigned long long* __restrict__ ws,
    int* __restrict__ out)
{
    __shared__ unsigned long long keys[NCAND];   // 64 KiB
    __shared__ int2     seb[LMAX];               // {s2e, e2s}
    __shared__ unsigned pays[TPB];               // transposed window payloads
    __shared__ unsigned acc_list[KOUT];
    __shared__ unsigned long long amask[SLOTS];
    __shared__ int      n_sh;
    __shared__ unsigned mkbuf[KOUT];
    __shared__ unsigned paybuf[KOUT];
    __shared__ int      cnt[KOUT * 4];

    const int sent = blockIdx.x;
    const int tid  = threadIdx.x;
    const unsigned long long* wi = ws + (long)sent * NCAND;

    if (tid < LMAX) seb[tid] = make_int2(-1, LMAX);
    if (tid == 0) n_sh = 0;

    for (int i = tid; i < NCAND; i += TPB) keys[i] = wi[i];
    __syncthreads();

    // ---- stage 1: merge (c0,c1)->[0,4096), (c2,c3)->[4096,8192) ------------
    {
        const int pair = tid >> 8;
        const int o    = (tid & 255) * 16;
        const unsigned long long* A = keys + pair * 4096;
        const unsigned long long* B = A + CHUNK;
        int lo = (o > CHUNK) ? o - CHUNK : 0;
        int hi = (o < CHUNK) ? o : CHUNK;
        while (lo < hi) {
            int mid = (lo + hi) >> 1;
            if (A[mid] <= B[o - 1 - mid]) lo = mid + 1; else hi = mid;
        }
        int i = lo, j = o - lo;
        unsigned long long r[16];
        #pragma unroll
        for (int x = 0; x < 16; ++x) {
            bool ta = (j >= CHUNK) || (i < CHUNK && A[i] <= B[j]);
            r[x] = ta ? A[i++] : B[j++];
        }
        __syncthreads();
        unsigned long long* O = keys + pair * 4096 + o;
        #pragma unroll
        for (int x = 0; x < 16; ++x) O[x] = r[x];
    }
    __syncthreads();

    // ---- stage 2: merge [0,4096)+[4096,8192) -> [0,8192) -------------------
    {
        const int o = tid * 16;
        const unsigned long long* A = keys;
        const unsigned long long* B = keys + 4096;
        int lo = (o > 4096) ? o - 4096 : 0;
        int hi = (o < 4096) ? o : 4096;
        while (lo < hi) {
            int mid = (lo + hi) >> 1;
            if (A[mid] <= B[o - 1 - mid]) lo = mid + 1; else hi = mid;
        }
        int i = lo, j = o - lo;
        unsigned long long r[16];
        #pragma unroll
        for (int x = 0; x < 16; ++x) {
            bool ta = (j >= 4096) || (i < 4096 && A[i] <= B[j]);
            r[x] = ta ? A[i++] : B[j++];
        }
        __syncthreads();
        #pragma unroll
        for (int x = 0; x < 16; ++x) keys[o + x] = r[x];
    }

    // ---- greedy non-crossing selection -------------------------------------
    for (int w = 0; w < NWIN; ++w) {
        const int cb = w * TPB;
        __syncthreads();                       // (1) seb / n_sh from prev window
        const int n0 = n_sh;
        if (n0 >= KOUT) break;                 // uniform

        // window filter: unrolled, break-free -> independent LDS reads.
        // crossing iff exists j in (st,en] with s2e[j] > en,
        //          or exists j in [st,en) with e2s[j] < st
        const unsigned pay = (unsigned)keys[cb + tid];
        const int en = (int)(pay & 511u);
        const int st = (int)((pay >> 9) & 511u);
        bool cross = false;
        {
            int j = st;
            for (; j + 4 <= en; j += 4) {      // j..j+3 all < en; j+1..j+3 > st
                int2 v0 = seb[j];
                int2 v1 = seb[j + 1];
                int2 v2 = seb[j + 2];
                int2 v3 = seb[j + 3];
                cross = cross | (((j > st) & (v0.x > en)) | (v0.y < st))
                              | ((v1.x > en) | (v1.y < st))
                              | ((v2.x > en) | (v2.y < st))
                              | ((v3.x > en) | (v3.y < st));
            }
            for (; j <= en; ++j) {
                int2 v = seb[j];
                cross = cross | (((j > st) & (v.x > en)) | ((j < en) & (v.y < st)));
            }
        }
        const unsigned long long m = __ballot((int)!cross);
        pays[(tid & 7) * 64 + (tid >> 3)] = pay;   // transpose: pays[s*64+l]
        if ((tid & 63) == 0) amask[tid >> 6] = m;
        __syncthreads();                       // (2) pays/amask visible

        if (tid < 64) {                        // accept loop: wave 0, lane-major
            const int lane = tid;
            // lane l owns candidates cb + l*8 + s, s=0..7 (candidate order = (l,s) lex)
            unsigned alive8 = (unsigned)((amask[lane >> 3] >> ((lane & 7) * 8)) & 0xFFull);
            unsigned pv[SLOTS];
            #pragma unroll
            for (int s = 0; s < SLOTS; ++s) pv[s] = pays[s * 64 + lane];
            int n = n0;
            for (;;) {
                const int sl = __ffs((int)alive8) - 1;   // my first alive slot (-1 if none)
                unsigned firstp = pv[0];
                #pragma unroll
                for (int s = 1; s < SLOTS; ++s) firstp = (sl == s) ? pv[s] : firstp;
                const unsigned long long anyb = __ballot(alive8 != 0u);
                if (anyb == 0ull) break;                 // window exhausted (uniform)
                const int lwin = __ffsll((long long)anyb) - 1;   // uniform
                const unsigned spay = READLANE(firstp, lwin);
                const int sen = (int)(spay & 511u);
                const int sst = (int)((spay >> 9) & 511u);
                if (lane == 0) acc_list[n] = spay;
                ++n;
                if (lane == lwin) alive8 &= ~(1u << sl);
                if (n >= KOUT) break;
                if (alive8) {                            // retest survivors vs new span
                    #pragma unroll
                    for (int s = 0; s < SLOTS; ++s) {
                        if ((alive8 >> s) & 1u) {
                            const int ce = (int)(pv[s] & 511u);
                            const int cs = (int)((pv[s] >> 9) & 511u);
                            const bool c = ((cs < sst) & (sst <= ce) & (sen > ce)) |
                                           ((sst < cs) & (sen >= cs) & (sen < ce));
                            if (c) alive8 &= ~(1u << s);
                        }
                    }
                }
            }
            if (lane == 0) n_sh = n;
        }
        __syncthreads();                       // (3) acc_list / n_sh visible

        // rebuild seb from this window's delta accepts (parallel atomics)
        const int n1 = n_sh;
        if (tid < n1 - n0) {
            unsigned ap = acc_list[n0 + tid];
            int ae = (int)(ap & 511u), as = (int)((ap >> 9) & 511u);
            atomicMax(&seb[as].x, ae);
            atomicMin(&seb[ae].y, as);
        }
    }
    __syncthreads();

    // ---- final (start,end) rank-sort (parallel count) + output -------------
    const int n = n_sh;
    if (tid < KOUT) {
        unsigned p = (tid < n) ? acc_list[tid] : acc_list[0];
        paybuf[tid] = p;
        mkbuf[tid]  = ((p & 0x3FFFFu) << 7) | (unsigned)tid;   // stable tie-break
    }
    __syncthreads();
    {
        const int i = tid >> 2, q = tid & 3;
        const unsigned mk = mkbuf[i];
        int c = 0;
        #pragma unroll
        for (int x = 0; x < 32; ++x) c += (mkbuf[q * 32 + x] < mk) ? 1 : 0;
        cnt[(i << 2) | q] = c;
    }
    __syncthreads();
    if (tid < KOUT) {
        const int r = cnt[tid * 4] + cnt[tid * 4 + 1] + cnt[tid * 4 + 2] + cnt[tid * 4 + 3];
        out[sent * KOUT + r] = (int)(paybuf[tid] >> 18);
    }
}

// ---------------------------------------------------------------------------
// Fallback monolithic kernel (round-2, known-correct) if ws is too small.
// ---------------------------------------------------------------------------
__global__ __launch_bounds__(TPB) void extract_spans_mono(
    const float* __restrict__ scores,
    const int*   __restrict__ starts,
    const int*   __restrict__ ends,
    int*         __restrict__ out)
{
    __shared__ unsigned long long keys[NCAND];
    __shared__ unsigned acc_list[KOUT];
    __shared__ unsigned long long amask[TPB/64];
    __shared__ unsigned mkbuf[KOUT];
    __shared__ unsigned paybuf[KOUT];

    const int  sent = blockIdx.x;
    const int  tid  = threadIdx.x;
    const long base = (long)sent * NCAND;

    for (int i = tid; i < NCAND; i += TPB) {
        unsigned u = __float_as_uint(scores[base + i]);
        unsigned o = (u & 0x80000000u) ? ~u : (u | 0x80000000u);
        unsigned d = ~o;
        unsigned st = (unsigned)starts[base + i];
        unsigned en = (unsigned)ends[base + i];
        keys[i] = ((unsigned long long)d << 32) | ((unsigned)i << 18) | (st << 9) | en;
    }
    for (int k = 2; k <= NCAND; k <<= 1) {
        for (int j = k >> 1; j > 0; j >>= 1) {
            __syncthreads();
            for (int p = tid; p < NCAND / 2; p += TPB) {
                int low = p & (j - 1);
                int i   = ((p - low) << 1) | low;
                int q   = i | j;
                unsigned long long a = keys[i];
                unsigned long long b = keys[q];
                bool up = ((i & k) == 0);
                if ((a > b) == up) { keys[i] = b; keys[q] = a; }
            }
        }
    }
    __syncthreads();

    int  nn   = 0;
    bool done = false;
    for (int cb = 0; cb < NCAND && !done; cb += TPB) {
        const unsigned pay = (unsigned)keys[cb + tid];
        const int en = (int)(pay & 511u);
        const int st = (int)((pay >> 9) & 511u);
        bool alive = true;
        for (int a = 0; a < nn; ++a) {
            unsigned ap = acc_list[a];
            int ae = (int)(ap & 511u), as = (int)((ap >> 9) & 511u);
            if ((st < as && as <= en && ae > en) || (as < st && ae >= st && ae < en)) {
                alive = false; break;
            }
        }
        for (;;) {
            unsigned long long m = __ballot((int)alive);
            if ((tid & 63) == 0) amask[tid >> 6] = m;
            __syncthreads();
            int s = -1;
            #pragma unroll
            for (int w = 0; w < TPB / 64; ++w) {
                unsigned long long mw = amask[w];
                if (s < 0 && mw) s = (w << 6) + __ffsll((long long)mw) - 1;
            }
            __syncthreads();
            if (s < 0) break;
            unsigned spay = (unsigned)keys[cb + s];
            int sen = (int)(spay & 511u), sst = (int)((spay >> 9) & 511u);
            if (tid == 0) acc_list[nn] = spay;
            ++nn;
            if (nn == KOUT) { done = true; break; }
            if (alive) {
                alive = (tid != s) &&
                        !((st < sst && sst <= en && sen > en) ||
                          (sst < st && sen >= st && sen < en));
            }
        }
    }
    __syncthreads();
    if (tid < KOUT) {
        unsigned pay = (tid < nn) ? acc_list[tid] : acc_list[0];
        paybuf[tid] = pay;
        mkbuf[tid]  = ((pay & 0x3FFFFu) << 7) | (unsigned)tid;
    }
    __syncthreads();
    if (tid < KOUT) {
        unsigned mk = mkbuf[tid];
        int rank = 0;
        for (int t2 = 0; t2 < KOUT; ++t2)
            rank += (mkbuf[t2] < mk) ? 1 : 0;
        out[sent * KOUT + rank] = (int)(paybuf[tid] >> 18);
    }
}

extern "C" void kernel_launch(void* const* d_in, const int* in_sizes, int n_in,
                              void* d_out, int out_size, void* d_ws, size_t ws_size,
                              hipStream_t stream) {
    const float* scores = (const float*)d_in[0];
    const int*   starts = (const int*)d_in[1];
    const int*   ends   = (const int*)d_in[2];
    int*         out    = (int*)d_out;

    const size_t ws_needed = (size_t)NSENT * NCAND * sizeof(unsigned long long); // 4 MiB
    if (ws_size >= ws_needed) {
        unsigned long long* ws = (unsigned long long*)d_ws;
        sort_chunks_kernel<<<NSENT * NCHUNK, TPB, 0, stream>>>(scores, starts, ends, ws);
        merge_greedy_kernel<<<NSENT, TPB, 0, stream>>>(ws, out);
    } else {
        extract_spans_mono<<<NSENT, TPB, 0, stream>>>(scores, starts, ends, out);
    }
}

// Round 7
// 161.997 us; speedup vs baseline: 1.3687x; 1.1872x over previous
//
#include <hip/hip_runtime.h>

#define NSENT 64
#define NCAND 8192
#define LMAX  512
#define KOUT  128
#define TPB   512
#define CHUNK 1024
#define NCHUNK (NCAND / CHUNK)   // 8
#define NWIN   (NCAND / TPB)     // 16
#define SLOTS  (TPB / 64)        // 8

#if defined(__has_builtin)
#if __has_builtin(__builtin_amdgcn_readlane)
#define READLANE(v, l) __builtin_amdgcn_readlane((unsigned)(v), (unsigned)(l))
#endif
#endif
#ifndef READLANE
#define READLANE(v, l) ((unsigned)__shfl((int)(v), (int)(l)))
#endif

// ---------------------------------------------------------------------------
// Kernel A: 512 blocks (sentence s = bid>>3, chunk c = bid&7).
// Bitonic-sort 1024 u64 keys in LDS (8 KiB -> 2 blocks/CU resident), -> ws.
// Key: high 32 = descending-orderable score bits, low 31 = (idx<<18)|(st<<9)|en
// ---------------------------------------------------------------------------
__global__ __launch_bounds__(TPB) void sort_chunks_kernel(
    const float* __restrict__ scores,
    const int*   __restrict__ starts,
    const int*   __restrict__ ends,
    unsigned long long* __restrict__ ws)
{
    __shared__ unsigned long long lk[CHUNK];
    const int  bid   = blockIdx.x;
    const int  sent  = bid >> 3;
    const int  chunk = bid & 7;
    const int  tid   = threadIdx.x;
    const long gbase = (long)sent * NCAND + (long)chunk * CHUNK;

    for (int i = tid; i < CHUNK; i += TPB) {
        unsigned u  = __float_as_uint(scores[gbase + i]);
        unsigned o  = (u & 0x80000000u) ? ~u : (u | 0x80000000u); // asc-orderable
        unsigned d  = ~o;                                          // descending
        unsigned st = (unsigned)starts[gbase + i];
        unsigned en = (unsigned)ends[gbase + i];
        unsigned gi = (unsigned)(chunk * CHUNK + i);               // idx in sentence
        lk[i] = ((unsigned long long)d << 32) | (gi << 18) | (st << 9) | en;
    }

    for (int k = 2; k <= CHUNK; k <<= 1) {
        for (int j = k >> 1; j > 0; j >>= 1) {
            __syncthreads();
            const int p   = tid;               // CHUNK/2 == TPB: one CX per thread
            const int low = p & (j - 1);
            const int i   = ((p - low) << 1) | low;
            const int q   = i | j;
            unsigned long long a = lk[i];
            unsigned long long b = lk[q];
            bool up = ((i & k) == 0);
            if ((a > b) == up) { lk[i] = b; lk[q] = a; }
        }
    }
    __syncthreads();

    unsigned long long* wo = ws + (long)bid * CHUNK;
    for (int i = tid; i < CHUNK; i += TPB) wo[i] = lk[i];
}

// ---------------------------------------------------------------------------
// Kernel B: 64 blocks (one per sentence).
//  1. load 8 sorted chunks, merge-path merge in 3 stages (in-place, reg-staged)
//  2. greedy non-crossing selection over 16 windows:
//     - O(1) filter: sparse range-max(s2e)/range-min(e2s) tables, 4 LDS reads
//     - accept loop in wave 0, no barriers; tables updated incrementally per
//       accept by a 62-lane parallel LDS-atomic burst (fire-and-forget)
//     - 2 block barriers per window
//  3. parallel rank-sort of the <=128 selected by (start,end)
// ---------------------------------------------------------------------------
__global__ __launch_bounds__(TPB) void merge_greedy_kernel(
    const unsigned long long* __restrict__ ws,
    int* __restrict__ out)
{
    __shared__ __align__(16) unsigned long long keys[NCAND];  // 64 KiB
    // TT1[k][i] = max s2e over [i, i+2^k) ; TT2[k][i] = min e2s over [i, i+2^k)
    __shared__ int TT1[5][LMAX];              // 10 KiB
    __shared__ int TT2[5][LMAX];              // 10 KiB
    __shared__ unsigned pays[TPB];            // transposed window payloads
    __shared__ unsigned acc_list[KOUT];
    __shared__ unsigned long long amask[SLOTS];
    __shared__ int      n_sh;
    __shared__ unsigned mkbuf[KOUT];
    __shared__ unsigned paybuf[KOUT];
    __shared__ int      cnt[KOUT * 4];

    const int sent = blockIdx.x;
    const int tid  = threadIdx.x;
    const unsigned long long* wi = ws + (long)sent * NCAND;

    // init tables (5 levels each) + n
    for (int i = tid; i < 5 * LMAX; i += TPB) {
        (&TT1[0][0])[i] = -1;
        (&TT2[0][0])[i] = LMAX;
    }
    if (tid == 0) n_sh = 0;

    // load keys as 16B packets
    {
        const ulonglong2* wi2 = (const ulonglong2*)wi;
        ulonglong2* k2 = (ulonglong2*)keys;
        for (int i = tid; i < NCAND / 2; i += TPB) k2[i] = wi2[i];
    }
    __syncthreads();

    // ---- merge: 8 sorted runs of 1024 -> 1 run of 8192 (3 stages) ----------
    #pragma unroll
    for (int stg = 0; stg < 3; ++stg) {
        const int Lh  = CHUNK << stg;          // 1024, 2048, 4096
        const int tpp = Lh >> 3;               // threads per pair = 2*Lh/16
        const int pair = tid / tpp;
        const int o    = (tid % tpp) * 16;
        const unsigned long long* A = keys + pair * (Lh * 2);
        const unsigned long long* B = A + Lh;
        int lo = (o > Lh) ? o - Lh : 0;
        int hi = (o < Lh) ? o : Lh;
        while (lo < hi) {                      // smallest i : A[i] > B[o-1-i]
            int mid = (lo + hi) >> 1;
            if (A[mid] <= B[o - 1 - mid]) lo = mid + 1; else hi = mid;
        }
        int i = lo, j = o - lo;
        unsigned long long r[16];
        #pragma unroll
        for (int x = 0; x < 16; ++x) {
            bool ta = (j >= Lh) || (i < Lh && A[i] <= B[j]);
            r[x] = ta ? A[i++] : B[j++];
        }
        __syncthreads();                       // all reads done before overwrite
        unsigned long long* O = keys + pair * (Lh * 2) + o;
        #pragma unroll
        for (int x = 0; x < 16; ++x) O[x] = r[x];
        __syncthreads();
    }

    // ---- greedy non-crossing selection over 16 windows ----------------------
    for (int w = 0; w < NWIN; ++w) {
        const int cb = w * TPB;
        const int n0 = n_sh;                   // after prev barrier
        if (n0 >= KOUT) break;                 // uniform

        // O(1) filter: crossing iff max s2e[st+1..en] > en  or
        //                           min e2s[st..en-1] < st     (wd = en-st)
        const unsigned pay = (unsigned)keys[cb + tid];
        const int en = (int)(pay & 511u);
        const int st = (int)((pay >> 9) & 511u);
        const int wd = en - st;
        bool cross = false;
        if (wd > 0) {
            if (wd < 32) {
                const int k   = 31 - __clz(wd);        // 0..4
                const int off = 1 << k;
                const int mx  = max(TT1[k][st + 1], TT1[k][en + 1 - off]);
                const int mn  = min(TT2[k][st],     TT2[k][en - off]);
                cross = (mx > en) || (mn < st);
            } else {                                    // cold path (wd>=32): scan level 0
                for (int j = st; j <= en; ++j)
                    cross |= ((j > st) && (TT1[0][j] > en)) || ((j < en) && (TT2[0][j] < st));
            }
        }
        const unsigned long long m = __ballot((int)!cross);
        pays[(tid & 7) * 64 + (tid >> 3)] = pay;        // pays[s*64+l] = cand l*8+s
        if ((tid & 63) == 0) amask[tid >> 6] = m;
        __syncthreads();                                // (A) pays/amask visible

        if (tid < 64) {                                 // accept loop: wave 0 only
            const int lane = tid;
            // lane l owns candidates cb + l*8 + s (candidate order = (l,s) lex)
            unsigned alive8 = (unsigned)((amask[lane >> 3] >> ((lane & 7) * 8)) & 0xFFull);
            unsigned pv[SLOTS];
            int cs[SLOTS], ce[SLOTS];
            #pragma unroll
            for (int s = 0; s < SLOTS; ++s) {
                pv[s] = pays[s * 64 + lane];
                ce[s] = (int)(pv[s] & 511u);
                cs[s] = (int)((pv[s] >> 9) & 511u);
            }
            // per-lane incremental-update role: accepted span (sst,sen) must bump
            // TT1[k][i] for i in [sst-2^k+1, sst] (31 cells) and TT2 likewise.
            const int sidel = (lane < 31) ? lane : (lane - 31);
            const int k_m   = 31 - __clz(sidel + 1);    // 0..4
            const int j_m   = sidel + 1 - (1 << k_m);   // 0..2^k-1
            int* const rowU = (lane < 31) ? &TT1[k_m][0] : &TT2[k_m][0];

            int n = n0;
            for (;;) {
                const unsigned long long anyb = __ballot(alive8 != 0u);
                if (anyb == 0ull) break;                // window exhausted (uniform)
                const int lwin = __ffsll((long long)anyb) - 1;
                const int sl   = __ffs((int)alive8) - 1;
                unsigned firstp = pv[0];
                #pragma unroll
                for (int s = 1; s < SLOTS; ++s) firstp = (sl == s) ? pv[s] : firstp;
                const unsigned spay = READLANE(firstp, lwin);
                const int sen = (int)(spay & 511u);
                const int sst = (int)((spay >> 9) & 511u);

                if (lane == 62) acc_list[n] = spay;
                if (lane < 31)      { const int i = sst - j_m; if (i >= 0) atomicMax(&rowU[i], sen); }
                else if (lane < 62) { const int i = sen - j_m; if (i >= 0) atomicMin(&rowU[i], sst); }
                if (lane == lwin) alive8 &= ~(1u << sl);
                ++n;
                if (n >= KOUT) break;
                #pragma unroll
                for (int s = 0; s < SLOTS; ++s) {       // branch-free retest vs new span
                    const bool c = ((cs[s] < sst) & (sst <= ce[s]) & (sen > ce[s])) |
                                   ((sst < cs[s]) & (sen >= cs[s]) & (sen < ce[s]));
                    alive8 &= ~(((unsigned)c) << s);
                }
            }
            if (lane == 0) n_sh = n;
        }
        __syncthreads();                                // (B) n_sh/tables/acc_list visible
    }

    // ---- final (start,end) rank-sort (parallel count) + output --------------
    const int n = n_sh;
    if (tid < KOUT) {
        unsigned p = (tid < n) ? acc_list[tid] : acc_list[0];
        paybuf[tid] = p;
        mkbuf[tid]  = ((p & 0x3FFFFu) << 7) | (unsigned)tid;   // stable tie-break
    }
    __syncthreads();
    {
        const int i = tid >> 2, q = tid & 3;
        const unsigned mk = mkbuf[i];
        int c = 0;
        #pragma unroll
        for (int x = 0; x < 32; ++x) c += (mkbuf[q * 32 + x] < mk) ? 1 : 0;
        cnt[(i << 2) | q] = c;
    }
    __syncthreads();
    if (tid < KOUT) {
        const int r = cnt[tid * 4] + cnt[tid * 4 + 1] + cnt[tid * 4 + 2] + cnt[tid * 4 + 3];
        out[sent * KOUT + r] = (int)(paybuf[tid] >> 18);
    }
}

// ---------------------------------------------------------------------------
// Fallback monolithic kernel (round-2, known-correct) if ws is too small.
// ---------------------------------------------------------------------------
__global__ __launch_bounds__(TPB) void extract_spans_mono(
    const float* __restrict__ scores,
    const int*   __restrict__ starts,
    const int*   __restrict__ ends,
    int*         __restrict__ out)
{
    __shared__ unsigned long long keys[NCAND];
    __shared__ unsigned acc_list[KOUT];
    __shared__ unsigned long long amask[TPB/64];
    __shared__ unsigned mkbuf[KOUT];
    __shared__ unsigned paybuf[KOUT];

    const int  sent = blockIdx.x;
    const int  tid  = threadIdx.x;
    const long base = (long)sent * NCAND;

    for (int i = tid; i < NCAND; i += TPB) {
        unsigned u = __float_as_uint(scores[base + i]);
        unsigned o = (u & 0x80000000u) ? ~u : (u | 0x80000000u);
        unsigned d = ~o;
        unsigned st = (unsigned)starts[base + i];
        unsigned en = (unsigned)ends[base + i];
        keys[i] = ((unsigned long long)d << 32) | ((unsigned)i << 18) | (st << 9) | en;
    }
    for (int k = 2; k <= NCAND; k <<= 1) {
        for (int j = k >> 1; j > 0; j >>= 1) {
            __syncthreads();
            for (int p = tid; p < NCAND / 2; p += TPB) {
                int low = p & (j - 1);
                int i   = ((p - low) << 1) | low;
                int q   = i | j;
                unsigned long long a = keys[i];
                unsigned long long b = keys[q];
                bool up = ((i & k) == 0);
                if ((a > b) == up) { keys[i] = b; keys[q] = a; }
            }
        }
    }
    __syncthreads();

    int  nn   = 0;
    bool done = false;
    for (int cb = 0; cb < NCAND && !done; cb += TPB) {
        const unsigned pay = (unsigned)keys[cb + tid];
        const int en = (int)(pay & 511u);
        const int st = (int)((pay >> 9) & 511u);
        bool alive = true;
        for (int a = 0; a < nn; ++a) {
            unsigned ap = acc_list[a];
            int ae = (int)(ap & 511u), as = (int)((ap >> 9) & 511u);
            if ((st < as && as <= en && ae > en) || (as < st && ae >= st && ae < en)) {
                alive = false; break;
            }
        }
        for (;;) {
            unsigned long long m = __ballot((int)alive);
            if ((tid & 63) == 0) amask[tid >> 6] = m;
            __syncthreads();
            int s = -1;
            #pragma unroll
            for (int w = 0; w < TPB / 64; ++w) {
                unsigned long long mw = amask[w];
                if (s < 0 && mw) s = (w << 6) + __ffsll((long long)mw) - 1;
            }
            __syncthreads();
            if (s < 0) break;
            unsigned spay = (unsigned)keys[cb + s];
            int sen = (int)(spay & 511u), sst = (int)((spay >> 9) & 511u);
            if (tid == 0) acc_list[nn] = spay;
            ++nn;
            if (nn == KOUT) { done = true; break; }
            if (alive) {
                alive = (tid != s) &&
                        !((st < sst && sst <= en && sen > en) ||
                          (sst < st && sen >= st && sen < en));
            }
        }
    }
    __syncthreads();
    if (tid < KOUT) {
        unsigned pay = (tid < nn) ? acc_list[tid] : acc_list[0];
        paybuf[tid] = pay;
        mkbuf[tid]  = ((pay & 0x3FFFFu) << 7) | (unsigned)tid;
    }
    __syncthreads();
    if (tid < KOUT) {
        unsigned mk = mkbuf[tid];
        int rank = 0;
        for (int t2 = 0; t2 < KOUT; ++t2)
            rank += (mkbuf[t2] < mk) ? 1 : 0;
        out[sent * KOUT + rank] = (int)(paybuf[tid] >> 18);
    }
}

extern "C" void kernel_launch(void* const* d_in, const int* in_sizes, int n_in,
                              void* d_out, int out_size, void* d_ws, size_t ws_size,
                              hipStream_t stream) {
    const float* scores = (const float*)d_in[0];
    const int*   starts = (const int*)d_in[1];
    const int*   ends   = (const int*)d_in[2];
    int*         out    = (int*)d_out;

    const size_t ws_needed = (size_t)NSENT * NCAND * sizeof(unsigned long long); // 4 MiB
    if (ws_size >= ws_needed) {
        unsigned long long* ws = (unsigned long long*)d_ws;
        sort_chunks_kernel<<<NSENT * NCHUNK, TPB, 0, stream>>>(scores, starts, ends, ws);
        merge_greedy_kernel<<<NSENT, TPB, 0, stream>>>(ws, out);
    } else {
        extract_spans_mono<<<NSENT, TPB, 0, stream>>>(scores, starts, ends, out);
    }
}